// Round 1
// baseline (2897.480 us; speedup 1.0000x reference)
//
#include <hip/hip_runtime.h>
#include <hip/hip_bf16.h>

constexpr int BATCH = 4;
constexpr int MEMK  = 128;
constexpr int SEQT  = 2048;
constexpr int CDIM  = 768;
constexpr int NH    = 12;
constexpr int HD    = 64;
constexpr int LDIM  = MEMK + 1 + SEQT;   // 2177
constexpr int MROWS = BATCH * LDIM;      // 8708

// ---------------- fp32 tiled GEMM: 128x128 tile, BK=16, 256 thr, 8x8 micro ----------------
// QKV=true: W has leading dim 3C, epilogue scatters into Q/K/V (B,H,L,HD).
// QKV=false: W has leading dim C, epilogue writes plain row-major (MROWS x C).
template<int NLD, bool QKV>
__global__ __launch_bounds__(256)
void gemm128_kernel(const float* __restrict__ A, const float* __restrict__ W,
                    float* __restrict__ O0, float* __restrict__ O1, float* __restrict__ O2)
{
    __shared__ float As[16][128];
    __shared__ float Bs[16][128];
    const int tid  = threadIdx.x;
    const int row0 = blockIdx.y * 128;
    const int col0 = blockIdx.x * 128;
    const int tx = tid & 15, ty = tid >> 4;

    float acc[8][8];
#pragma unroll
    for (int i = 0; i < 8; ++i)
#pragma unroll
        for (int j = 0; j < 8; ++j) acc[i][j] = 0.f;

    for (int kt = 0; kt < CDIM / 16; ++kt) {
        // A tile 128x16, store transposed As[k][m]
#pragma unroll
        for (int i = 0; i < 2; ++i) {
            int fid = tid * 2 + i;
            int mm  = fid >> 2;
            int kq  = (fid & 3) * 4;
            int grow = row0 + mm;
            float4 a = make_float4(0.f, 0.f, 0.f, 0.f);
            if (grow < MROWS)
                a = *(const float4*)&A[(size_t)grow * CDIM + kt * 16 + kq];
            As[kq + 0][mm] = a.x; As[kq + 1][mm] = a.y;
            As[kq + 2][mm] = a.z; As[kq + 3][mm] = a.w;
        }
        // B tile 16x128 (vector writes)
#pragma unroll
        for (int i = 0; i < 2; ++i) {
            int fid = tid * 2 + i;
            int kr  = fid >> 5;
            int cq  = (fid & 31) * 4;
            *(float4*)&Bs[kr][cq] =
                *(const float4*)&W[(size_t)(kt * 16 + kr) * NLD + col0 + cq];
        }
        __syncthreads();
#pragma unroll
        for (int kk = 0; kk < 16; ++kk) {
            float av[8], bv[8];
#pragma unroll
            for (int i = 0; i < 8; ++i) av[i] = As[kk][ty * 8 + i];
#pragma unroll
            for (int j = 0; j < 8; ++j) bv[j] = Bs[kk][tx * 8 + j];
#pragma unroll
            for (int i = 0; i < 8; ++i)
#pragma unroll
                for (int j = 0; j < 8; ++j)
                    acc[i][j] += av[i] * bv[j];
        }
        __syncthreads();
    }

    if (QKV) {
        // n block of 8 consecutive cols stays within one (sel, h) group
        const int n0  = col0 + tx * 8;
        const int sel = n0 / CDIM;
        const int c0  = n0 % CDIM;
        const int h   = c0 / HD;
        const int dd0 = c0 % HD;
        float* outb = (sel == 0) ? O0 : (sel == 1 ? O1 : O2);
#pragma unroll
        for (int i = 0; i < 8; ++i) {
            int m = row0 + ty * 8 + i;
            if (m >= MROWS) break;
            int b = m / LDIM, l = m % LDIM;
            float* p = outb + (((size_t)b * NH + h) * LDIM + l) * HD + dd0;
            *(float4*)&p[0] = make_float4(acc[i][0], acc[i][1], acc[i][2], acc[i][3]);
            *(float4*)&p[4] = make_float4(acc[i][4], acc[i][5], acc[i][6], acc[i][7]);
        }
    } else {
#pragma unroll
        for (int i = 0; i < 8; ++i) {
            int m = row0 + ty * 8 + i;
            if (m >= MROWS) break;
            float* p = O0 + (size_t)m * CDIM + col0 + tx * 8;
            *(float4*)&p[0] = make_float4(acc[i][0], acc[i][1], acc[i][2], acc[i][3]);
            *(float4*)&p[4] = make_float4(acc[i][4], acc[i][5], acc[i][6], acc[i][7]);
        }
    }
}

// ---------------- flash attention, fp32, contiguous mask [0..kmax] ----------------
// 1 wave per block, 1 query row per thread, K/V tiles of 32 staged in LDS.
__global__ __launch_bounds__(64)
void attn_kernel(const float* __restrict__ Qb, const float* __restrict__ Kb,
                 const float* __restrict__ Vb, float* __restrict__ Y)
{
    __shared__ float Ks[32][64];
    __shared__ float Vs[32][64];
    const int bh = blockIdx.y;             // b*NH + h
    const int b  = bh / NH, h = bh % NH;
    const int qi = blockIdx.x * 64 + threadIdx.x;
    const bool active = qi < LDIM;

    const float* qptr = Qb + ((size_t)bh * LDIM + (active ? qi : LDIM - 1)) * HD;
    float q[64];
#pragma unroll
    for (int i = 0; i < 64; i += 4)
        *(float4*)&q[i] = *(const float4*)&qptr[i];

    // contiguous allowed-key bound (inclusive)
    const int kmax = !active ? -1
                   : (qi < MEMK ? MEMK : (qi == MEMK ? LDIM - 1 : qi));
    // block-level bound
    const int lo = blockIdx.x * 64;
    const int hi = min(lo + 63, LDIM - 1);
    const int blk_kmax = (MEMK >= lo && MEMK <= hi) ? (LDIM - 1)
                       : (hi < MEMK ? MEMK : hi);
    const int ntiles = (blk_kmax + 32) / 32;

    float mrun = -INFINITY, ssum = 0.f;
    float acc[64];
#pragma unroll
    for (int i = 0; i < 64; ++i) acc[i] = 0.f;

    const float* kbase = Kb + (size_t)bh * LDIM * HD;
    const float* vbase = Vb + (size_t)bh * LDIM * HD;

    for (int t = 0; t < ntiles; ++t) {
        const int k0 = t * 32;
        __syncthreads();
        // stage 32 keys + values (clamped at L-1; masked anyway)
#pragma unroll
        for (int i = 0; i < 8; ++i) {
            int f4 = i * 64 + threadIdx.x;          // 0..511
            int kr = f4 >> 4;
            int cc = (f4 & 15) * 4;
            int kidx = min(k0 + kr, LDIM - 1);
            *(float4*)&Ks[kr][cc] = *(const float4*)&kbase[(size_t)kidx * HD + cc];
            *(float4*)&Vs[kr][cc] = *(const float4*)&vbase[(size_t)kidx * HD + cc];
        }
        __syncthreads();

        if (active) {
            float s[32];
#pragma unroll
            for (int kk = 0; kk < 32; ++kk) {
                float d = 0.f;
#pragma unroll
                for (int dd = 0; dd < 64; ++dd)
                    d += q[dd] * Ks[kk][dd];
                s[kk] = (k0 + kk <= kmax) ? d * 0.125f : -INFINITY;
            }
            float tmax = mrun;
#pragma unroll
            for (int kk = 0; kk < 32; ++kk) tmax = fmaxf(tmax, s[kk]);
            float corr = __expf(mrun - tmax);
            mrun = tmax;
            ssum *= corr;
#pragma unroll
            for (int dd = 0; dd < 64; ++dd) acc[dd] *= corr;
#pragma unroll
            for (int kk = 0; kk < 32; ++kk) {
                float p = __expf(s[kk] - mrun);
                ssum += p;
#pragma unroll
                for (int dd = 0; dd < 64; ++dd)
                    acc[dd] += p * Vs[kk][dd];
            }
        }
    }

    if (active) {
        float inv = 1.f / ssum;
        float* yp = Y + ((size_t)b * LDIM + qi) * CDIM + h * HD;
#pragma unroll
        for (int dd = 0; dd < 64; dd += 4) {
            *(float4*)&yp[dd] = make_float4(acc[dd] * inv, acc[dd + 1] * inv,
                                            acc[dd + 2] * inv, acc[dd + 3] * inv);
        }
    }
}

extern "C" void kernel_launch(void* const* d_in, const int* in_sizes, int n_in,
                              void* d_out, int out_size, void* d_ws, size_t ws_size,
                              hipStream_t stream)
{
    const float* x      = (const float*)d_in[0];
    const float* W_attn = (const float*)d_in[1];
    const float* W_proj = (const float*)d_in[2];
    float* out = (float*)d_out;
    float* ws  = (float*)d_ws;

    const size_t per = (size_t)BATCH * NH * LDIM * HD;   // 6,687,744 floats
    float* Qb = ws;
    float* Kb = ws + per;
    float* Vb = ws + 2 * per;
    float* Yb = ws + 3 * per;                            // (B,L,C) flat

    // QKV projection: M=8708, N=2304
    gemm128_kernel<3 * CDIM, true><<<dim3(2304 / 128, (MROWS + 127) / 128), 256, 0, stream>>>(
        x, W_attn, Qb, Kb, Vb);

    // attention
    attn_kernel<<<dim3((LDIM + 63) / 64, BATCH * NH), 64, 0, stream>>>(Qb, Kb, Vb, Yb);

    // output projection: M=8708, N=768
    gemm128_kernel<CDIM, false><<<dim3(CDIM / 128, (MROWS + 127) / 128), 256, 0, stream>>>(
        Yb, W_proj, out, nullptr, nullptr);
}

// Round 2
// 1108.569 us; speedup vs baseline: 2.6137x; 2.6137x over previous
//
#include <hip/hip_runtime.h>
#include <hip/hip_bf16.h>

constexpr int BATCH = 4;
constexpr int MEMK  = 128;
constexpr int CDIM  = 768;
constexpr int NH    = 12;
constexpr int HD    = 64;
constexpr int LDIM  = 2177;              // MEMK + 1 + 2048
constexpr int MROWS = BATCH * LDIM;      // 8708
constexpr int LPAD  = 2240;              // Vt row length: mult of 8, >= ceil(L/64)*64

typedef __attribute__((ext_vector_type(4))) float f32x4;
typedef __attribute__((ext_vector_type(8))) short short8;

__device__ __forceinline__ short f2bf(float f) {
    unsigned u = __builtin_bit_cast(unsigned, f);
    u = (u + 0x7FFFu + ((u >> 16) & 1u)) >> 16;
    return (short)u;
}
__device__ __forceinline__ float bf2f(short s) {
    unsigned u = ((unsigned)(unsigned short)s) << 16;
    return __builtin_bit_cast(float, u);
}

// ---------------- QKV GEMM: fp32 mainloop, epilogue -> bf16 hi/lo planes ----------------
__global__ __launch_bounds__(256)
void gemm_qkv_kernel(const float* __restrict__ A, const float* __restrict__ W,
                     short* __restrict__ Qh, short* __restrict__ Ql,
                     short* __restrict__ Kh, short* __restrict__ Kl,
                     short* __restrict__ Vth, short* __restrict__ Vtl)
{
    __shared__ float As[16][128];
    __shared__ float Bs[16][128];
    const int tid  = threadIdx.x;
    const int row0 = blockIdx.y * 128;
    const int col0 = blockIdx.x * 128;
    const int tx = tid & 15, ty = tid >> 4;

    float acc[8][8];
#pragma unroll
    for (int i = 0; i < 8; ++i)
#pragma unroll
        for (int j = 0; j < 8; ++j) acc[i][j] = 0.f;

    for (int kt = 0; kt < CDIM / 16; ++kt) {
#pragma unroll
        for (int i = 0; i < 2; ++i) {
            int fid = tid * 2 + i;
            int mm  = fid >> 2;
            int kq  = (fid & 3) * 4;
            int grow = row0 + mm;
            float4 a = make_float4(0.f, 0.f, 0.f, 0.f);
            if (grow < MROWS)
                a = *(const float4*)&A[(size_t)grow * CDIM + kt * 16 + kq];
            As[kq + 0][mm] = a.x; As[kq + 1][mm] = a.y;
            As[kq + 2][mm] = a.z; As[kq + 3][mm] = a.w;
        }
#pragma unroll
        for (int i = 0; i < 2; ++i) {
            int fid = tid * 2 + i;
            int kr  = fid >> 5;
            int cq  = (fid & 31) * 4;
            *(float4*)&Bs[kr][cq] =
                *(const float4*)&W[(size_t)(kt * 16 + kr) * (3 * CDIM) + col0 + cq];
        }
        __syncthreads();
#pragma unroll
        for (int kk = 0; kk < 16; ++kk) {
            float av[8], bv[8];
#pragma unroll
            for (int i = 0; i < 8; ++i) av[i] = As[kk][ty * 8 + i];
#pragma unroll
            for (int j = 0; j < 8; ++j) bv[j] = Bs[kk][tx * 8 + j];
#pragma unroll
            for (int i = 0; i < 8; ++i)
#pragma unroll
                for (int j = 0; j < 8; ++j)
                    acc[i][j] += av[i] * bv[j];
        }
        __syncthreads();
    }

    const int n0  = col0 + tx * 8;
    const int sel = n0 / CDIM;
    const int c0  = n0 % CDIM;
    const int h   = c0 / HD;
    const int dd0 = c0 % HD;
#pragma unroll
    for (int i = 0; i < 8; ++i) {
        int m = row0 + ty * 8 + i;
        if (m >= MROWS) break;
        int b = m / LDIM, l = m % LDIM;
        short hs[8], ls[8];
#pragma unroll
        for (int j = 0; j < 8; ++j) {
            float v = acc[i][j];
            hs[j] = f2bf(v);
            ls[j] = f2bf(v - bf2f(hs[j]));
        }
        if (sel == 2) {
            size_t vb = ((size_t)(b * NH + h)) * HD * LPAD + l;
#pragma unroll
            for (int j = 0; j < 8; ++j) {
                Vth[vb + (size_t)(dd0 + j) * LPAD] = hs[j];
                Vtl[vb + (size_t)(dd0 + j) * LPAD] = ls[j];
            }
        } else {
            size_t base = (((size_t)(b * NH + h)) * LDIM + l) * HD + dd0;
            short* ph = (sel == 0) ? Qh : Kh;
            short* pl = (sel == 0) ? Ql : Kl;
            short8 vh, vl;
#pragma unroll
            for (int j = 0; j < 8; ++j) { vh[j] = hs[j]; vl[j] = ls[j]; }
            *(short8*)(ph + base) = vh;
            *(short8*)(pl + base) = vl;
        }
    }
}

// ---------------- MFMA flash attention (bf16 hi/lo split, fp32 accum) ----------------
// block = 256 thr = 4 waves; wave handles 32 q-rows; key tiles of 64.
__global__ __launch_bounds__(256)
void attn_mfma_kernel(const short* __restrict__ Qh, const short* __restrict__ Ql,
                      const short* __restrict__ Kh, const short* __restrict__ Kl,
                      const short* __restrict__ Vth, const short* __restrict__ Vtl,
                      float* __restrict__ Y)
{
    __shared__ float Pbuf[4][32][68];   // per-wave P bounce, stride 68 (16B-aligned rows, 2-way banks)
    const int lane = threadIdx.x & 63;
    const int w    = threadIdx.x >> 6;
    const int bh   = blockIdx.y;
    const int b = bh / NH, h = bh % NH;
    const int qbase = blockIdx.x * 128 + w * 32;
    if (qbase >= LDIM) return;
    const int lr = lane & 15, lg = lane >> 4;

    // per-row inclusive key bound
    int rkmax[2][4];
#pragma unroll
    for (int rg = 0; rg < 2; ++rg)
#pragma unroll
        for (int r = 0; r < 4; ++r) {
            int q = qbase + rg * 16 + lg * 4 + r;
            rkmax[rg][r] = (q < MEMK) ? MEMK
                         : (q == MEMK) ? (LDIM - 1)
                         : (q < LDIM) ? q : -1;
        }
    const int rlast = min(qbase + 31, LDIM - 1);
    const int wkmax = (rlast < MEMK) ? MEMK : ((qbase <= MEMK) ? (LDIM - 1) : rlast);
    const int ntiles = wkmax / 64 + 1;

    // Q fragments, resident all kernel
    short8 qfh[2][2], qfl[2][2];
#pragma unroll
    for (int rg = 0; rg < 2; ++rg)
#pragma unroll
        for (int dc = 0; dc < 2; ++dc) {
            int qr = min(qbase + rg * 16 + lr, LDIM - 1);
            size_t off = ((size_t)bh * LDIM + qr) * HD + dc * 32 + lg * 8;
            qfh[rg][dc] = *(const short8*)(Qh + off);
            qfl[rg][dc] = *(const short8*)(Ql + off);
        }

    f32x4 O[2][4];
    float mrun[2][4], lsum[2][4];
#pragma unroll
    for (int rg = 0; rg < 2; ++rg)
#pragma unroll
        for (int g = 0; g < 4; ++g) {
            O[rg][g] = (f32x4){0.f, 0.f, 0.f, 0.f};
            mrun[rg][g] = -INFINITY;
            lsum[rg][g] = 0.f;
        }

    const size_t kbase = (size_t)bh * LDIM * HD;
    const size_t vbase = (size_t)bh * HD * LPAD;

    for (int t = 0; t < ntiles; ++t) {
        const int k0 = t * 64;
        // ---- QK^T: S[rg][kg] = Q(16x64) . K^T, hi/lo triple ----
        f32x4 S[2][4];
#pragma unroll
        for (int kg = 0; kg < 4; ++kg) {
            int krow = min(k0 + kg * 16 + lr, LDIM - 1);
            short8 kfh[2], kfl[2];
#pragma unroll
            for (int dc = 0; dc < 2; ++dc) {
                size_t off = kbase + (size_t)krow * HD + dc * 32 + lg * 8;
                kfh[dc] = *(const short8*)(Kh + off);
                kfl[dc] = *(const short8*)(Kl + off);
            }
#pragma unroll
            for (int rg = 0; rg < 2; ++rg) {
                f32x4 acc = (f32x4){0.f, 0.f, 0.f, 0.f};
#pragma unroll
                for (int dc = 0; dc < 2; ++dc) {
                    acc = __builtin_amdgcn_mfma_f32_16x16x32_bf16(qfh[rg][dc], kfh[dc], acc, 0, 0, 0);
                    acc = __builtin_amdgcn_mfma_f32_16x16x32_bf16(qfl[rg][dc], kfh[dc], acc, 0, 0, 0);
                    acc = __builtin_amdgcn_mfma_f32_16x16x32_bf16(qfh[rg][dc], kfl[dc], acc, 0, 0, 0);
                }
                S[rg][kg] = acc;
            }
        }
        // ---- mask + online softmax + P -> LDS ----
#pragma unroll
        for (int rg = 0; rg < 2; ++rg)
#pragma unroll
            for (int r = 0; r < 4; ++r) {
                float sv[4];
#pragma unroll
                for (int kg = 0; kg < 4; ++kg) {
                    int col = k0 + kg * 16 + lr;
                    float v = S[rg][kg][r] * 0.125f;
                    sv[kg] = (col <= rkmax[rg][r]) ? v : -INFINITY;
                }
                float mx = fmaxf(fmaxf(sv[0], sv[1]), fmaxf(sv[2], sv[3]));
#pragma unroll
                for (int d = 1; d < 16; d <<= 1) mx = fmaxf(mx, __shfl_xor(mx, d));
                float nm = fmaxf(mrun[rg][r], mx);
                float corr = (nm == -INFINITY) ? 1.f : __expf(mrun[rg][r] - nm);
                mrun[rg][r] = nm;
                float ps = 0.f;
#pragma unroll
                for (int kg = 0; kg < 4; ++kg) {
                    float p = (sv[kg] == -INFINITY) ? 0.f : __expf(sv[kg] - nm);
                    ps += p;
                    Pbuf[w][rg * 16 + lg * 4 + r][kg * 16 + lr] = p;
                }
#pragma unroll
                for (int d = 1; d < 16; d <<= 1) ps += __shfl_xor(ps, d);
                lsum[rg][r] = lsum[rg][r] * corr + ps;
#pragma unroll
                for (int g = 0; g < 4; ++g) O[rg][g][r] *= corr;
            }
        // ---- PV: O += P(32x64) . V(64x64), hi/lo triple, V from transposed planes ----
#pragma unroll
        for (int kkc = 0; kkc < 2; ++kkc) {
            short8 pfh[2], pfl[2];
#pragma unroll
            for (int rg = 0; rg < 2; ++rg) {
                const float* pp = &Pbuf[w][rg * 16 + lr][kkc * 32 + lg * 8];
                f32x4 pa = *(const f32x4*)pp;
                f32x4 pb = *(const f32x4*)(pp + 4);
#pragma unroll
                for (int e = 0; e < 4; ++e) {
                    pfh[rg][e] = f2bf(pa[e]);
                    pfl[rg][e] = f2bf(pa[e] - bf2f(pfh[rg][e]));
                    pfh[rg][4 + e] = f2bf(pb[e]);
                    pfl[rg][4 + e] = f2bf(pb[e] - bf2f(pfh[rg][4 + e]));
                }
            }
#pragma unroll
            for (int ddg = 0; ddg < 4; ++ddg) {
                size_t off = vbase + (size_t)(ddg * 16 + lr) * LPAD + k0 + kkc * 32 + lg * 8;
                short8 vh = *(const short8*)(Vth + off);
                short8 vl = *(const short8*)(Vtl + off);
#pragma unroll
                for (int rg = 0; rg < 2; ++rg) {
                    f32x4 acc = O[rg][ddg];
                    acc = __builtin_amdgcn_mfma_f32_16x16x32_bf16(pfh[rg], vh, acc, 0, 0, 0);
                    acc = __builtin_amdgcn_mfma_f32_16x16x32_bf16(pfh[rg], vl, acc, 0, 0, 0);
                    acc = __builtin_amdgcn_mfma_f32_16x16x32_bf16(pfl[rg], vh, acc, 0, 0, 0);
                    O[rg][ddg] = acc;
                }
            }
        }
    }
    // ---- normalize + store ----
#pragma unroll
    for (int rg = 0; rg < 2; ++rg)
#pragma unroll
        for (int r = 0; r < 4; ++r) {
            int q = qbase + rg * 16 + lg * 4 + r;
            if (q < LDIM) {
                float inv = 1.f / lsum[rg][r];
#pragma unroll
                for (int ddg = 0; ddg < 4; ++ddg)
                    Y[((size_t)b * LDIM + q) * CDIM + h * HD + ddg * 16 + lr] = O[rg][ddg][r] * inv;
            }
        }
}

// ---------------- output projection: plain fp32 GEMM ----------------
__global__ __launch_bounds__(256)
void gemm_out_kernel(const float* __restrict__ A, const float* __restrict__ W,
                     float* __restrict__ Out)
{
    __shared__ float As[16][128];
    __shared__ float Bs[16][128];
    const int tid  = threadIdx.x;
    const int row0 = blockIdx.y * 128;
    const int col0 = blockIdx.x * 128;
    const int tx = tid & 15, ty = tid >> 4;

    float acc[8][8];
#pragma unroll
    for (int i = 0; i < 8; ++i)
#pragma unroll
        for (int j = 0; j < 8; ++j) acc[i][j] = 0.f;

    for (int kt = 0; kt < CDIM / 16; ++kt) {
#pragma unroll
        for (int i = 0; i < 2; ++i) {
            int fid = tid * 2 + i;
            int mm  = fid >> 2;
            int kq  = (fid & 3) * 4;
            int grow = row0 + mm;
            float4 a = make_float4(0.f, 0.f, 0.f, 0.f);
            if (grow < MROWS)
                a = *(const float4*)&A[(size_t)grow * CDIM + kt * 16 + kq];
            As[kq + 0][mm] = a.x; As[kq + 1][mm] = a.y;
            As[kq + 2][mm] = a.z; As[kq + 3][mm] = a.w;
        }
#pragma unroll
        for (int i = 0; i < 2; ++i) {
            int fid = tid * 2 + i;
            int kr  = fid >> 5;
            int cq  = (fid & 31) * 4;
            *(float4*)&Bs[kr][cq] =
                *(const float4*)&W[(size_t)(kt * 16 + kr) * CDIM + col0 + cq];
        }
        __syncthreads();
#pragma unroll
        for (int kk = 0; kk < 16; ++kk) {
            float av[8], bv[8];
#pragma unroll
            for (int i = 0; i < 8; ++i) av[i] = As[kk][ty * 8 + i];
#pragma unroll
            for (int j = 0; j < 8; ++j) bv[j] = Bs[kk][tx * 8 + j];
#pragma unroll
            for (int i = 0; i < 8; ++i)
#pragma unroll
                for (int j = 0; j < 8; ++j)
                    acc[i][j] += av[i] * bv[j];
        }
        __syncthreads();
    }
#pragma unroll
    for (int i = 0; i < 8; ++i) {
        int m = row0 + ty * 8 + i;
        if (m >= MROWS) break;
        float* p = Out + (size_t)m * CDIM + col0 + tx * 8;
        *(float4*)&p[0] = make_float4(acc[i][0], acc[i][1], acc[i][2], acc[i][3]);
        *(float4*)&p[4] = make_float4(acc[i][4], acc[i][5], acc[i][6], acc[i][7]);
    }
}

extern "C" void kernel_launch(void* const* d_in, const int* in_sizes, int n_in,
                              void* d_out, int out_size, void* d_ws, size_t ws_size,
                              hipStream_t stream)
{
    const float* x      = (const float*)d_in[0];
    const float* W_attn = (const float*)d_in[1];
    const float* W_proj = (const float*)d_in[2];
    float* out = (float*)d_out;

    const size_t qkN = (size_t)BATCH * NH * LDIM * HD;   // shorts per Q/K plane
    const size_t vtN = (size_t)BATCH * NH * HD * LPAD;   // shorts per Vt plane
    char* p = (char*)d_ws;
    short* Qh  = (short*)p; p += qkN * 2;
    short* Ql  = (short*)p; p += qkN * 2;
    short* Kh  = (short*)p; p += qkN * 2;
    short* Kl  = (short*)p; p += qkN * 2;
    short* Vth = (short*)p; p += vtN * 2;
    short* Vtl = (short*)p; p += vtN * 2;
    float* Yb  = (float*)p;

    gemm_qkv_kernel<<<dim3(2304 / 128, (MROWS + 127) / 128), 256, 0, stream>>>(
        x, W_attn, Qh, Ql, Kh, Kl, Vth, Vtl);

    attn_mfma_kernel<<<dim3((LDIM + 127) / 128, BATCH * NH), 256, 0, stream>>>(
        Qh, Ql, Kh, Kl, Vth, Vtl, Yb);

    gemm_out_kernel<<<dim3(CDIM / 128, (MROWS + 127) / 128), 256, 0, stream>>>(
        Yb, W_proj, out);
}

// Round 6
// 697.066 us; speedup vs baseline: 4.1567x; 1.5903x over previous
//
#include <hip/hip_runtime.h>
#include <hip/hip_bf16.h>

constexpr int BATCH = 4;
constexpr int MEMK  = 128;
constexpr int CDIM  = 768;
constexpr int NH    = 12;
constexpr int HD    = 64;
constexpr int LDIM  = 2177;              // MEMK + 1 + 2048
constexpr int MROWS = BATCH * LDIM;      // 8708
constexpr int LPAD  = 2240;              // Vt row length

typedef __attribute__((ext_vector_type(4))) float f32x4;
typedef __attribute__((ext_vector_type(8))) short short8;

__device__ __forceinline__ short f2bf(float f) {
    unsigned u = __builtin_bit_cast(unsigned, f);
    u = (u + 0x7FFFu + ((u >> 16) & 1u)) >> 16;
    return (short)u;
}
__device__ __forceinline__ float bf2f(short s) {
    unsigned u = ((unsigned)(unsigned short)s) << 16;
    return __builtin_bit_cast(float, u);
}
__device__ __forceinline__ void split2(float v, short& h, short& l) {
    h = f2bf(v);
    l = f2bf(v - bf2f(h));
}
__device__ __forceinline__ void gload16(const void* g, void* l) {
    __builtin_amdgcn_global_load_lds(
        (const __attribute__((address_space(1))) void*)g,
        (__attribute__((address_space(3))) void*)l, 16, 0, 0);
}

// ---------------- convert fp32 -> bf16 hi/lo planes (row-major) ----------------
__global__ __launch_bounds__(256)
void convsplit_kernel(const float* __restrict__ src, short* __restrict__ h,
                      short* __restrict__ l, int n4)
{
    for (int i = blockIdx.x * blockDim.x + threadIdx.x; i < n4;
         i += gridDim.x * blockDim.x) {
        float4 v = ((const float4*)src)[i];
        short hs[4], ls[4];
        split2(v.x, hs[0], ls[0]); split2(v.y, hs[1], ls[1]);
        split2(v.z, hs[2], ls[2]); split2(v.w, hs[3], ls[3]);
        ((short4*)h)[i] = make_short4(hs[0], hs[1], hs[2], hs[3]);
        ((short4*)l)[i] = make_short4(ls[0], ls[1], ls[2], ls[3]);
    }
}

// ---------------- transpose + convert: W[K][N] -> Wt hi/lo [N][K] ----------------
__global__ __launch_bounds__(256)
void transconv_kernel(const float* __restrict__ W, short* __restrict__ th,
                      short* __restrict__ tl, int K, int N)
{
    __shared__ float tile[32][33];
    const int k0 = blockIdx.y * 32, n0 = blockIdx.x * 32;
    const int tx = threadIdx.x & 31, ty = threadIdx.x >> 5;   // 32 x 8
#pragma unroll
    for (int j = 0; j < 4; ++j)
        tile[ty + j * 8][tx] = W[(size_t)(k0 + ty + j * 8) * N + n0 + tx];
    __syncthreads();
#pragma unroll
    for (int j = 0; j < 4; ++j) {
        float v = tile[tx][ty + j * 8];
        short hi, lo; split2(v, hi, lo);
        size_t o = (size_t)(n0 + ty + j * 8) * K + k0 + tx;
        th[o] = hi; tl[o] = lo;
    }
}

// ---------------- MFMA GEMM: A[M][768] (hi/lo) x Bt[N][768] (hi/lo) ----------------
// 128x128 tile, BK=32, 4 waves (2x2), hi/lo triple -> fp32-grade accuracy.
// EPI: 0 = QKV scatter epilogue, 1 = plain fp32 out epilogue.
template<int EPI>
__global__ __launch_bounds__(256)
void gemm_mfma_kernel(const short* __restrict__ Ah, const short* __restrict__ Al,
                      const short* __restrict__ Bh, const short* __restrict__ Bl,
                      short* __restrict__ Qh, short* __restrict__ Ql,
                      short* __restrict__ Kh, short* __restrict__ Kl,
                      short* __restrict__ Vth, short* __restrict__ Vtl,
                      float* __restrict__ Of)
{
    constexpr int KD = 768;
    __shared__ short lds[4][128 * 32];   // Ah, Al, Bh, Bl tiles (8KB each)
    const int tid  = threadIdx.x;
    const int lane = tid & 63;
    const int w    = tid >> 6;
    const int wr = w >> 1, wc = w & 1;
    const int lr = lane & 15, lg = lane >> 4;
    const int row0 = blockIdx.y * 128, col0 = blockIdx.x * 128;

    f32x4 acc[4][4];
#pragma unroll
    for (int m = 0; m < 4; ++m)
#pragma unroll
        for (int n = 0; n < 4; ++n) acc[m][n] = (f32x4){0.f, 0.f, 0.f, 0.f};

    for (int kt = 0; kt < KD / 32; ++kt) {
        const int k0 = kt * 32;
        __syncthreads();   // previous iteration's reads complete
#pragma unroll
        for (int q = 0; q < 2; ++q) {
            const int c = q * 256 + tid;       // chunk id: 16B each
            const int r = c >> 2, s = c & 3;
            const int ar = min(row0 + r, MROWS - 1);
            const int br = col0 + r;
            const size_t aoff = (size_t)ar * KD + k0 + s * 8;
            const size_t boff = (size_t)br * KD + k0 + s * 8;
            gload16(Ah + aoff, &lds[0][c * 8]);
            gload16(Al + aoff, &lds[1][c * 8]);
            gload16(Bh + boff, &lds[2][c * 8]);
            gload16(Bl + boff, &lds[3][c * 8]);
        }
        __syncthreads();   // vmcnt(0) drained by compiler before barrier

        short8 afh[4], afl[4], bfh[4], bfl[4];
#pragma unroll
        for (int m = 0; m < 4; ++m) {
            int r = wr * 64 + m * 16 + lr;
            afh[m] = *(const short8*)&lds[0][r * 32 + lg * 8];
            afl[m] = *(const short8*)&lds[1][r * 32 + lg * 8];
        }
#pragma unroll
        for (int n = 0; n < 4; ++n) {
            int r = wc * 64 + n * 16 + lr;
            bfh[n] = *(const short8*)&lds[2][r * 32 + lg * 8];
            bfl[n] = *(const short8*)&lds[3][r * 32 + lg * 8];
        }
#pragma unroll
        for (int m = 0; m < 4; ++m)
#pragma unroll
            for (int n = 0; n < 4; ++n) {
                f32x4 a = acc[m][n];
                a = __builtin_amdgcn_mfma_f32_16x16x32_bf16(afh[m], bfh[n], a, 0, 0, 0);
                a = __builtin_amdgcn_mfma_f32_16x16x32_bf16(afl[m], bfh[n], a, 0, 0, 0);
                a = __builtin_amdgcn_mfma_f32_16x16x32_bf16(afh[m], bfl[n], a, 0, 0, 0);
                acc[m][n] = a;
            }
    }

    // ---- epilogue ----
#pragma unroll
    for (int n = 0; n < 4; ++n) {
        const int colb = col0 + wc * 64 + n * 16;
        if (EPI == 0) {
            const int sel = colb / CDIM;
            const int c0  = colb - sel * CDIM;
            const int h   = c0 >> 6;
            const int dd  = (c0 & 63) + lr;
#pragma unroll
            for (int m = 0; m < 4; ++m)
#pragma unroll
                for (int e = 0; e < 4; ++e) {
                    int mg = row0 + wr * 64 + m * 16 + lg * 4 + e;
                    if (mg >= MROWS) continue;
                    int b = mg / LDIM, l = mg - b * LDIM;
                    short hi, lo; split2(acc[m][n][e], hi, lo);
                    if (sel == 0) {
                        size_t o = (((size_t)(b * NH + h)) * LDIM + l) * HD + dd;
                        Qh[o] = hi; Ql[o] = lo;
                    } else if (sel == 1) {
                        size_t o = (((size_t)(b * NH + h)) * LDIM + l) * HD + dd;
                        Kh[o] = hi; Kl[o] = lo;
                    } else {
                        size_t o = (((size_t)(b * NH + h)) * HD + dd) * LPAD + l;
                        Vth[o] = hi; Vtl[o] = lo;
                    }
                }
        } else {
#pragma unroll
            for (int m = 0; m < 4; ++m)
#pragma unroll
                for (int e = 0; e < 4; ++e) {
                    int mg = row0 + wr * 64 + m * 16 + lg * 4 + e;
                    if (mg >= MROWS) continue;
                    Of[(size_t)mg * CDIM + colb + lr] = acc[m][n][e];
                }
        }
    }
}

// ---------------- MFMA flash attention (bf16 hi/lo split, fp32 accum) ----------------
__global__ __launch_bounds__(256)
void attn_mfma_kernel(const short* __restrict__ Qh, const short* __restrict__ Ql,
                      const short* __restrict__ Kh, const short* __restrict__ Kl,
                      const short* __restrict__ Vth, const short* __restrict__ Vtl,
                      short* __restrict__ Yh, short* __restrict__ Yl)
{
    __shared__ float Pbuf[4][32][68];
    const int lane = threadIdx.x & 63;
    const int w    = threadIdx.x >> 6;
    const int bh   = blockIdx.y;
    const int b = bh / NH, h = bh % NH;
    const int qbase = blockIdx.x * 128 + w * 32;
    if (qbase >= LDIM) return;
    const int lr = lane & 15, lg = lane >> 4;

    int rkmax[2][4];
#pragma unroll
    for (int rg = 0; rg < 2; ++rg)
#pragma unroll
        for (int r = 0; r < 4; ++r) {
            int q = qbase + rg * 16 + lg * 4 + r;
            rkmax[rg][r] = (q < MEMK) ? MEMK
                         : (q == MEMK) ? (LDIM - 1)
                         : (q < LDIM) ? q : -1;
        }
    const int rlast = min(qbase + 31, LDIM - 1);
    const int wkmax = (rlast < MEMK) ? MEMK : ((qbase <= MEMK) ? (LDIM - 1) : rlast);
    const int ntiles = wkmax / 64 + 1;

    short8 qfh[2][2], qfl[2][2];
#pragma unroll
    for (int rg = 0; rg < 2; ++rg)
#pragma unroll
        for (int dc = 0; dc < 2; ++dc) {
            int qr = min(qbase + rg * 16 + lr, LDIM - 1);
            size_t off = ((size_t)bh * LDIM + qr) * HD + dc * 32 + lg * 8;
            qfh[rg][dc] = *(const short8*)(Qh + off);
            qfl[rg][dc] = *(const short8*)(Ql + off);
        }

    f32x4 O[2][4];
    float mrun[2][4], lsum[2][4];
#pragma unroll
    for (int rg = 0; rg < 2; ++rg)
#pragma unroll
        for (int g = 0; g < 4; ++g) {
            O[rg][g] = (f32x4){0.f, 0.f, 0.f, 0.f};
            mrun[rg][g] = -INFINITY;
            lsum[rg][g] = 0.f;
        }

    const size_t kbase = (size_t)bh * LDIM * HD;
    const size_t vbase = (size_t)bh * HD * LPAD;

    for (int t = 0; t < ntiles; ++t) {
        const int k0 = t * 64;
        f32x4 S[2][4];
#pragma unroll
        for (int kg = 0; kg < 4; ++kg) {
            int krow = min(k0 + kg * 16 + lr, LDIM - 1);
            short8 kfh[2], kfl[2];
#pragma unroll
            for (int dc = 0; dc < 2; ++dc) {
                size_t off = kbase + (size_t)krow * HD + dc * 32 + lg * 8;
                kfh[dc] = *(const short8*)(Kh + off);
                kfl[dc] = *(const short8*)(Kl + off);
            }
#pragma unroll
            for (int rg = 0; rg < 2; ++rg) {
                f32x4 a = (f32x4){0.f, 0.f, 0.f, 0.f};
#pragma unroll
                for (int dc = 0; dc < 2; ++dc) {
                    a = __builtin_amdgcn_mfma_f32_16x16x32_bf16(qfh[rg][dc], kfh[dc], a, 0, 0, 0);
                    a = __builtin_amdgcn_mfma_f32_16x16x32_bf16(qfl[rg][dc], kfh[dc], a, 0, 0, 0);
                    a = __builtin_amdgcn_mfma_f32_16x16x32_bf16(qfh[rg][dc], kfl[dc], a, 0, 0, 0);
                }
                S[rg][kg] = a;
            }
        }
#pragma unroll
        for (int rg = 0; rg < 2; ++rg)
#pragma unroll
            for (int r = 0; r < 4; ++r) {
                float sv[4];
#pragma unroll
                for (int kg = 0; kg < 4; ++kg) {
                    int col = k0 + kg * 16 + lr;
                    float v = S[rg][kg][r] * 0.125f;
                    sv[kg] = (col <= rkmax[rg][r]) ? v : -INFINITY;
                }
                float mx = fmaxf(fmaxf(sv[0], sv[1]), fmaxf(sv[2], sv[3]));
#pragma unroll
                for (int d = 1; d < 16; d <<= 1) mx = fmaxf(mx, __shfl_xor(mx, d));
                float nm = fmaxf(mrun[rg][r], mx);
                float corr = (nm == -INFINITY) ? 1.f : __expf(mrun[rg][r] - nm);
                mrun[rg][r] = nm;
                float ps = 0.f;
#pragma unroll
                for (int kg = 0; kg < 4; ++kg) {
                    float p = (sv[kg] == -INFINITY) ? 0.f : __expf(sv[kg] - nm);
                    ps += p;
                    Pbuf[w][rg * 16 + lg * 4 + r][kg * 16 + lr] = p;
                }
#pragma unroll
                for (int d = 1; d < 16; d <<= 1) ps += __shfl_xor(ps, d);
                lsum[rg][r] = lsum[rg][r] * corr + ps;
#pragma unroll
                for (int g = 0; g < 4; ++g) O[rg][g][r] *= corr;
            }
#pragma unroll
        for (int kkc = 0; kkc < 2; ++kkc) {
            short8 pfh[2], pfl[2];
#pragma unroll
            for (int rg = 0; rg < 2; ++rg) {
                const float* pp = &Pbuf[w][rg * 16 + lr][kkc * 32 + lg * 8];
                f32x4 pa = *(const f32x4*)pp;
                f32x4 pb = *(const f32x4*)(pp + 4);
#pragma unroll
                for (int e = 0; e < 4; ++e) {
                    short h0, l0, h1, l1;
                    split2(pa[e], h0, l0);
                    split2(pb[e], h1, l1);
                    pfh[rg][e] = h0; pfl[rg][e] = l0;
                    pfh[rg][4 + e] = h1; pfl[rg][4 + e] = l1;
                }
            }
#pragma unroll
            for (int ddg = 0; ddg < 4; ++ddg) {
                size_t off = vbase + (size_t)(ddg * 16 + lr) * LPAD + k0 + kkc * 32 + lg * 8;
                short8 vh = *(const short8*)(Vth + off);
                short8 vl = *(const short8*)(Vtl + off);
#pragma unroll
                for (int rg = 0; rg < 2; ++rg) {
                    f32x4 a = O[rg][ddg];
                    a = __builtin_amdgcn_mfma_f32_16x16x32_bf16(pfh[rg], vh, a, 0, 0, 0);
                    a = __builtin_amdgcn_mfma_f32_16x16x32_bf16(pfh[rg], vl, a, 0, 0, 0);
                    a = __builtin_amdgcn_mfma_f32_16x16x32_bf16(pfl[rg], vh, a, 0, 0, 0);
                    O[rg][ddg] = a;
                }
            }
        }
    }
#pragma unroll
    for (int rg = 0; rg < 2; ++rg)
#pragma unroll
        for (int r = 0; r < 4; ++r) {
            int q = qbase + rg * 16 + lg * 4 + r;
            if (q < LDIM) {
                float inv = 1.f / lsum[rg][r];
#pragma unroll
                for (int ddg = 0; ddg < 4; ++ddg) {
                    float v = O[rg][ddg][r] * inv;
                    short hi, lo; split2(v, hi, lo);
                    size_t o = ((size_t)b * LDIM + q) * CDIM + h * HD + ddg * 16 + lr;
                    Yh[o] = hi; Yl[o] = lo;
                }
            }
        }
}

extern "C" void kernel_launch(void* const* d_in, const int* in_sizes, int n_in,
                              void* d_out, int out_size, void* d_ws, size_t ws_size,
                              hipStream_t stream)
{
    const float* x      = (const float*)d_in[0];
    const float* W_attn = (const float*)d_in[1];
    const float* W_proj = (const float*)d_in[2];
    float* out = (float*)d_out;

    const size_t xN  = (size_t)MROWS * CDIM;             // 6,687,744
    const size_t waN = (size_t)CDIM * 3 * CDIM;          // 1,769,472
    const size_t wpN = (size_t)CDIM * CDIM;              //   589,824
    const size_t qkN = (size_t)BATCH * NH * LDIM * HD;
    const size_t vtN = (size_t)BATCH * NH * HD * LPAD;

    char* p = (char*)d_ws;
    short* Xh  = (short*)p; p += xN * 2;    // aliased later as Yh
    short* Xl  = (short*)p; p += xN * 2;    // aliased later as Yl
    short* Wth = (short*)p; p += waN * 2;
    short* Wtl = (short*)p; p += waN * 2;
    short* Pth = (short*)p; p += wpN * 2;
    short* Ptl = (short*)p; p += wpN * 2;
    short* Qh  = (short*)p; p += qkN * 2;
    short* Ql  = (short*)p; p += qkN * 2;
    short* Kh  = (short*)p; p += qkN * 2;
    short* Kl  = (short*)p; p += qkN * 2;
    short* Vth = (short*)p; p += vtN * 2;
    short* Vtl = (short*)p; p += vtN * 2;
    short* Yh = Xh;   // x dead after QKV GEMM
    short* Yl = Xl;

    convsplit_kernel<<<2048, 256, 0, stream>>>(x, Xh, Xl, (int)(xN / 4));
    transconv_kernel<<<dim3(3 * CDIM / 32, CDIM / 32), 256, 0, stream>>>(
        W_attn, Wth, Wtl, CDIM, 3 * CDIM);
    transconv_kernel<<<dim3(CDIM / 32, CDIM / 32), 256, 0, stream>>>(
        W_proj, Pth, Ptl, CDIM, CDIM);

    gemm_mfma_kernel<0><<<dim3(3 * CDIM / 128, (MROWS + 127) / 128), 256, 0, stream>>>(
        Xh, Xl, Wth, Wtl, Qh, Ql, Kh, Kl, Vth, Vtl, nullptr);

    attn_mfma_kernel<<<dim3((LDIM + 127) / 128, BATCH * NH), 256, 0, stream>>>(
        Qh, Ql, Kh, Kl, Vth, Vtl, Yh, Yl);

    gemm_mfma_kernel<1><<<dim3(CDIM / 128, (MROWS + 127) / 128), 256, 0, stream>>>(
        Yh, Yl, Pth, Ptl, nullptr, nullptr, nullptr, nullptr, nullptr, nullptr, out);
}

// Round 7
// 531.504 us; speedup vs baseline: 5.4515x; 1.3115x over previous
//
#include <hip/hip_runtime.h>
#include <hip/hip_bf16.h>

constexpr int BATCH = 4;
constexpr int MEMK  = 128;
constexpr int CDIM  = 768;
constexpr int NH    = 12;
constexpr int HD    = 64;
constexpr int LDIM  = 2177;              // MEMK + 1 + 2048
constexpr int MROWS = BATCH * LDIM;      // 8708
constexpr int LPAD  = 2240;              // Vt row length

typedef __attribute__((ext_vector_type(4))) float f32x4;
typedef __attribute__((ext_vector_type(8))) short short8;
typedef __attribute__((ext_vector_type(4))) short s16x4;

__device__ __forceinline__ short f2bf(float f) {
    unsigned u = __builtin_bit_cast(unsigned, f);
    u = (u + 0x7FFFu + ((u >> 16) & 1u)) >> 16;
    return (short)u;
}
__device__ __forceinline__ float bf2f(short s) {
    unsigned u = ((unsigned)(unsigned short)s) << 16;
    return __builtin_bit_cast(float, u);
}
__device__ __forceinline__ void split2(float v, short& h, short& l) {
    h = f2bf(v);
    l = f2bf(v - bf2f(h));
}
__device__ __forceinline__ void gload16(const void* g, void* l) {
    __builtin_amdgcn_global_load_lds(
        (const __attribute__((address_space(1))) void*)g,
        (__attribute__((address_space(3))) void*)l, 16, 0, 0);
}

// ---------------- convert fp32 -> bf16 hi/lo planes (row-major) ----------------
__global__ __launch_bounds__(256)
void convsplit_kernel(const float* __restrict__ src, short* __restrict__ h,
                      short* __restrict__ l, int n4)
{
    for (int i = blockIdx.x * blockDim.x + threadIdx.x; i < n4;
         i += gridDim.x * blockDim.x) {
        float4 v = ((const float4*)src)[i];
        short hs[4], ls[4];
        split2(v.x, hs[0], ls[0]); split2(v.y, hs[1], ls[1]);
        split2(v.z, hs[2], ls[2]); split2(v.w, hs[3], ls[3]);
        ((short4*)h)[i] = make_short4(hs[0], hs[1], hs[2], hs[3]);
        ((short4*)l)[i] = make_short4(ls[0], ls[1], ls[2], ls[3]);
    }
}

// ---------------- transpose + convert: W[K][N] -> Wt hi/lo [N][K] ----------------
__global__ __launch_bounds__(256)
void transconv_kernel(const float* __restrict__ W, short* __restrict__ th,
                      short* __restrict__ tl, int K, int N)
{
    __shared__ float tile[32][33];
    const int k0 = blockIdx.y * 32, n0 = blockIdx.x * 32;
    const int tx = threadIdx.x & 31, ty = threadIdx.x >> 5;   // 32 x 8
#pragma unroll
    for (int j = 0; j < 4; ++j)
        tile[ty + j * 8][tx] = W[(size_t)(k0 + ty + j * 8) * N + n0 + tx];
    __syncthreads();
#pragma unroll
    for (int j = 0; j < 4; ++j) {
        float v = tile[tx][ty + j * 8];
        short hi, lo; split2(v, hi, lo);
        size_t o = (size_t)(n0 + ty + j * 8) * K + k0 + tx;
        th[o] = hi; tl[o] = lo;
    }
}

// ---------------- MFMA GEMM: A[M][768] (hi/lo) x Bt[N][768] (hi/lo) ----------------
// EPI: 0 = QKV scatter epilogue (Q pre-scaled by 0.125), 1 = plain fp32 out.
template<int EPI>
__global__ __launch_bounds__(256)
void gemm_mfma_kernel(const short* __restrict__ Ah, const short* __restrict__ Al,
                      const short* __restrict__ Bh, const short* __restrict__ Bl,
                      short* __restrict__ Qh, short* __restrict__ Ql,
                      short* __restrict__ Kh, short* __restrict__ Kl,
                      short* __restrict__ Vth, short* __restrict__ Vtl,
                      float* __restrict__ Of)
{
    constexpr int KD = 768;
    __shared__ short lds[4][128 * 32];   // Ah, Al, Bh, Bl tiles (8KB each)
    const int tid  = threadIdx.x;
    const int lane = tid & 63;
    const int w    = tid >> 6;
    const int wr = w >> 1, wc = w & 1;
    const int lr = lane & 15, lg = lane >> 4;
    const int row0 = blockIdx.y * 128, col0 = blockIdx.x * 128;

    f32x4 acc[4][4];
#pragma unroll
    for (int m = 0; m < 4; ++m)
#pragma unroll
        for (int n = 0; n < 4; ++n) acc[m][n] = (f32x4){0.f, 0.f, 0.f, 0.f};

    for (int kt = 0; kt < KD / 32; ++kt) {
        const int k0 = kt * 32;
        __syncthreads();
#pragma unroll
        for (int q = 0; q < 2; ++q) {
            const int c = q * 256 + tid;
            const int r = c >> 2, s = c & 3;
            const int ar = min(row0 + r, MROWS - 1);
            const int br = col0 + r;
            const size_t aoff = (size_t)ar * KD + k0 + s * 8;
            const size_t boff = (size_t)br * KD + k0 + s * 8;
            gload16(Ah + aoff, &lds[0][c * 8]);
            gload16(Al + aoff, &lds[1][c * 8]);
            gload16(Bh + boff, &lds[2][c * 8]);
            gload16(Bl + boff, &lds[3][c * 8]);
        }
        __syncthreads();

        short8 afh[4], afl[4], bfh[4], bfl[4];
#pragma unroll
        for (int m = 0; m < 4; ++m) {
            int r = wr * 64 + m * 16 + lr;
            afh[m] = *(const short8*)&lds[0][r * 32 + lg * 8];
            afl[m] = *(const short8*)&lds[1][r * 32 + lg * 8];
        }
#pragma unroll
        for (int n = 0; n < 4; ++n) {
            int r = wc * 64 + n * 16 + lr;
            bfh[n] = *(const short8*)&lds[2][r * 32 + lg * 8];
            bfl[n] = *(const short8*)&lds[3][r * 32 + lg * 8];
        }
#pragma unroll
        for (int m = 0; m < 4; ++m)
#pragma unroll
            for (int n = 0; n < 4; ++n) {
                f32x4 a = acc[m][n];
                a = __builtin_amdgcn_mfma_f32_16x16x32_bf16(afh[m], bfh[n], a, 0, 0, 0);
                a = __builtin_amdgcn_mfma_f32_16x16x32_bf16(afl[m], bfh[n], a, 0, 0, 0);
                a = __builtin_amdgcn_mfma_f32_16x16x32_bf16(afh[m], bfl[n], a, 0, 0, 0);
                acc[m][n] = a;
            }
    }

#pragma unroll
    for (int n = 0; n < 4; ++n) {
        const int colb = col0 + wc * 64 + n * 16;
        if (EPI == 0) {
            const int sel = colb / CDIM;
            const int c0  = colb - sel * CDIM;
            const int h   = c0 >> 6;
            const int dd  = (c0 & 63) + lr;
            const float scl = (sel == 0) ? 0.125f : 1.0f;   // exact: Q pre-scale
#pragma unroll
            for (int m = 0; m < 4; ++m)
#pragma unroll
                for (int e = 0; e < 4; ++e) {
                    int mg = row0 + wr * 64 + m * 16 + lg * 4 + e;
                    if (mg >= MROWS) continue;
                    int b = mg / LDIM, l = mg - b * LDIM;
                    short hi, lo; split2(acc[m][n][e] * scl, hi, lo);
                    if (sel == 0) {
                        size_t o = (((size_t)(b * NH + h)) * LDIM + l) * HD + dd;
                        Qh[o] = hi; Ql[o] = lo;
                    } else if (sel == 1) {
                        size_t o = (((size_t)(b * NH + h)) * LDIM + l) * HD + dd;
                        Kh[o] = hi; Kl[o] = lo;
                    } else {
                        size_t o = (((size_t)(b * NH + h)) * HD + dd) * LPAD + l;
                        Vth[o] = hi; Vtl[o] = lo;
                    }
                }
        } else {
#pragma unroll
            for (int m = 0; m < 4; ++m)
#pragma unroll
                for (int e = 0; e < 4; ++e) {
                    int mg = row0 + wr * 64 + m * 16 + lg * 4 + e;
                    if (mg >= MROWS) continue;
                    Of[(size_t)mg * CDIM + colb + lr] = acc[m][n][e];
                }
        }
    }
}

// ---------------- MFMA flash attention v2 ----------------
// Swapped QK^T (D[key][q], lane-local softmax rows), block-staged K/V in LDS
// (pre-swizzled global_load_lds), bf16 P bounce, heavy-first block order.
__global__ __launch_bounds__(256)
void attn_mfma_kernel(const short* __restrict__ Qh, const short* __restrict__ Ql,
                      const short* __restrict__ Kh, const short* __restrict__ Kl,
                      const short* __restrict__ Vth, const short* __restrict__ Vtl,
                      short* __restrict__ Yh, short* __restrict__ Yl)
{
    __shared__ short Klds[2][64 * 64];   // [plane][key][d] XOR-swizzled, 16KB
    __shared__ short Vlds[2][64 * 64];   // [plane][d][key] XOR-swizzled, 16KB
    __shared__ short Pqs[4][2][32 * 64]; // [wave][plane][q][key] swizzled, 32KB
    const int tid  = threadIdx.x;
    const int lane = tid & 63;
    const int w    = tid >> 6;
    const int lr = lane & 15, lg = lane >> 4;
    const int bh = blockIdx.y;
    const int b = bh / NH, h = bh % NH;
    constexpr int NXB = (LDIM + 127) / 128;          // 18
    const int qb = (NXB - 1 - (int)blockIdx.x) * 128; // heavy blocks first
    const int qw = qb + w * 32;

    // tile counts (contiguous mask: row q sees keys [0..kmax(q)])
    int mynt;
    if (qw >= LDIM) mynt = 0;
    else if (qw <= MEMK && MEMK <= qw + 31) mynt = (LDIM - 1) / 64 + 1;
    else if (qw + 31 < MEMK) mynt = MEMK / 64 + 1;
    else mynt = min(qw + 31, LDIM - 1) / 64 + 1;
    int bnt;
    if (qb <= MEMK && MEMK <= qb + 127) bnt = (LDIM - 1) / 64 + 1;
    else if (qb + 127 < MEMK) bnt = MEMK / 64 + 1;
    else bnt = min(qb + 127, LDIM - 1) / 64 + 1;

    int rkmax[2];
#pragma unroll
    for (int rg = 0; rg < 2; ++rg) {
        int q = qw + rg * 16 + lr;
        rkmax[rg] = (q < MEMK) ? MEMK : (q == MEMK) ? (LDIM - 1)
                  : (q < LDIM) ? q : -1;
    }

    // Q fragments (B-operand), pre-scaled by 0.125 at QKV epilogue
    short8 qfh[2][2], qfl[2][2];
#pragma unroll
    for (int rg = 0; rg < 2; ++rg)
#pragma unroll
        for (int dc = 0; dc < 2; ++dc) {
            int qr = min(qw + rg * 16 + lr, LDIM - 1);
            size_t off = ((size_t)bh * LDIM + qr) * HD + dc * 32 + lg * 8;
            qfh[rg][dc] = *(const short8*)(Qh + off);
            qfl[rg][dc] = *(const short8*)(Ql + off);
        }

    f32x4 O[2][4];
#pragma unroll
    for (int rg = 0; rg < 2; ++rg)
#pragma unroll
        for (int g = 0; g < 4; ++g) O[rg][g] = (f32x4){0.f, 0.f, 0.f, 0.f};
    float mrun[2] = {-INFINITY, -INFINITY};
    float lsum[2] = {0.f, 0.f};

    const short* Khb = Kh  + (size_t)bh * LDIM * HD;
    const short* Klb = Kl  + (size_t)bh * LDIM * HD;
    const short* Vhb = Vth + (size_t)bh * HD * LPAD;
    const short* Vlb = Vtl + (size_t)bh * HD * LPAD;

    for (int t = 0; t < bnt; ++t) {
        const int k0 = t * 64;
        __syncthreads();                 // prev-tile LDS reads complete
        // ---- stage K/V tile, source pre-swizzled so swizzled-read works ----
#pragma unroll
        for (int it = 0; it < 2; ++it) {
            int c = it * 256 + tid;      // 16B chunk id, lane-stride 16B
            int row = c >> 3, j = c & 7;
            int sw = ((j ^ (row & 7)) << 3);
            gload16(Khb + (size_t)(k0 + row) * HD + sw, &Klds[0][c * 8]);
            gload16(Klb + (size_t)(k0 + row) * HD + sw, &Klds[1][c * 8]);
            gload16(Vhb + (size_t)row * LPAD + k0 + sw, &Vlds[0][c * 8]);
            gload16(Vlb + (size_t)row * LPAD + k0 + sw, &Vlds[1][c * 8]);
        }
        __syncthreads();                 // vmcnt drained by compiler

        if (t < mynt) {
            // ---- QK^T swapped: S[key][q], A=K from LDS, B=Q regs ----
            f32x4 S[2][4];
#pragma unroll
            for (int kg = 0; kg < 4; ++kg) {
                short8 kfh[2], kfl[2];
#pragma unroll
                for (int dc = 0; dc < 2; ++dc) {
                    int key = kg * 16 + lr;
                    int cj = (dc * 4 + lg) ^ (key & 7);
                    kfh[dc] = *(const short8*)&Klds[0][key * 64 + cj * 8];
                    kfl[dc] = *(const short8*)&Klds[1][key * 64 + cj * 8];
                }
#pragma unroll
                for (int rg = 0; rg < 2; ++rg) {
                    f32x4 a = (f32x4){0.f, 0.f, 0.f, 0.f};
#pragma unroll
                    for (int dc = 0; dc < 2; ++dc) {
                        a = __builtin_amdgcn_mfma_f32_16x16x32_bf16(kfh[dc], qfh[rg][dc], a, 0, 0, 0);
                        a = __builtin_amdgcn_mfma_f32_16x16x32_bf16(kfl[dc], qfh[rg][dc], a, 0, 0, 0);
                        a = __builtin_amdgcn_mfma_f32_16x16x32_bf16(kfh[dc], qfl[rg][dc], a, 0, 0, 0);
                    }
                    S[rg][kg] = a;
                }
            }
            // ---- softmax: rows lane-local, 2 shfl per reduce ----
            float corr2[2];
#pragma unroll
            for (int rg = 0; rg < 2; ++rg) {
                const int rel = rkmax[rg] - k0 - lg * 4;
                float mx = -INFINITY;
#pragma unroll
                for (int kg = 0; kg < 4; ++kg)
#pragma unroll
                    for (int e = 0; e < 4; ++e) {
                        float v = S[rg][kg][e];
                        v = (kg * 16 + e <= rel) ? v : -INFINITY;
                        S[rg][kg][e] = v;
                        mx = fmaxf(mx, v);
                    }
                mx = fmaxf(mx, __shfl_xor(mx, 16));
                mx = fmaxf(mx, __shfl_xor(mx, 32));
                float nm = fmaxf(mrun[rg], mx);
                float corr = (nm == -INFINITY) ? 1.f : __expf(mrun[rg] - nm);
                mrun[rg] = nm;
                float ps = 0.f;
                const int qq = rg * 16 + lr;
#pragma unroll
                for (int kg = 0; kg < 4; ++kg) {
                    s16x4 h4, l4;
#pragma unroll
                    for (int e = 0; e < 4; ++e) {
                        float v = S[rg][kg][e];
                        float pp = (v == -INFINITY) ? 0.f : __expf(v - nm);
                        ps += pp;
                        short hh, ll; split2(pp, hh, ll);
                        h4[e] = hh; l4[e] = ll;
                    }
                    int c8 = (kg * 4 + lg) ^ (qq & 7);
                    *(s16x4*)&Pqs[w][0][qq * 64 + c8 * 4] = h4;
                    *(s16x4*)&Pqs[w][1][qq * 64 + c8 * 4] = l4;
                }
                ps += __shfl_xor(ps, 16);
                ps += __shfl_xor(ps, 32);
                lsum[rg] = lsum[rg] * corr + ps;
                corr2[rg] = corr;
            }
            // ---- rescale O (corr redistributed q=lr -> q=lg*4+e) ----
#pragma unroll
            for (int rg = 0; rg < 2; ++rg)
#pragma unroll
                for (int e = 0; e < 4; ++e) {
                    float cc = __shfl(corr2[rg], lg * 4 + e);
#pragma unroll
                    for (int ddg = 0; ddg < 4; ++ddg) O[rg][ddg][e] *= cc;
                }
            // ---- PV: A=P (bf16 from LDS), B=V (LDS) ----
#pragma unroll
            for (int kkc = 0; kkc < 2; ++kkc) {
                short8 ph[2], pl[2];
#pragma unroll
                for (int rg = 0; rg < 2; ++rg) {
                    const int qq = rg * 16 + lr, s = qq & 7;
                    const int c0 = kkc * 8 + lg * 2;
                    s16x4 a0 = *(const s16x4*)&Pqs[w][0][qq * 64 + ((c0) ^ s) * 4];
                    s16x4 a1 = *(const s16x4*)&Pqs[w][0][qq * 64 + ((c0 + 1) ^ s) * 4];
                    s16x4 b0 = *(const s16x4*)&Pqs[w][1][qq * 64 + ((c0) ^ s) * 4];
                    s16x4 b1 = *(const s16x4*)&Pqs[w][1][qq * 64 + ((c0 + 1) ^ s) * 4];
                    short8 p8, q8;
#pragma unroll
                    for (int e = 0; e < 4; ++e) {
                        p8[e] = a0[e]; p8[4 + e] = a1[e];
                        q8[e] = b0[e]; q8[4 + e] = b1[e];
                    }
                    ph[rg] = p8; pl[rg] = q8;
                }
#pragma unroll
                for (int ddg = 0; ddg < 4; ++ddg) {
                    int d = ddg * 16 + lr;
                    int cj = (kkc * 4 + lg) ^ (d & 7);
                    short8 vh = *(const short8*)&Vlds[0][d * 64 + cj * 8];
                    short8 vl = *(const short8*)&Vlds[1][d * 64 + cj * 8];
#pragma unroll
                    for (int rg = 0; rg < 2; ++rg) {
                        f32x4 a = O[rg][ddg];
                        a = __builtin_amdgcn_mfma_f32_16x16x32_bf16(ph[rg], vh, a, 0, 0, 0);
                        a = __builtin_amdgcn_mfma_f32_16x16x32_bf16(ph[rg], vl, a, 0, 0, 0);
                        a = __builtin_amdgcn_mfma_f32_16x16x32_bf16(pl[rg], vh, a, 0, 0, 0);
                        O[rg][ddg] = a;
                    }
                }
            }
        }
    }
    // ---- epilogue ----
#pragma unroll
    for (int rg = 0; rg < 2; ++rg) {
        float invv = (lsum[rg] > 0.f) ? 1.f / lsum[rg] : 0.f;
#pragma unroll
        for (int e = 0; e < 4; ++e) {
            float ie = __shfl(invv, lg * 4 + e);
            int q = qw + rg * 16 + lg * 4 + e;
            if (q < LDIM) {
#pragma unroll
                for (int ddg = 0; ddg < 4; ++ddg) {
                    float v = O[rg][ddg][e] * ie;
                    short hi, lo; split2(v, hi, lo);
                    size_t o = ((size_t)b * LDIM + q) * CDIM + h * HD + ddg * 16 + lr;
                    Yh[o] = hi; Yl[o] = lo;
                }
            }
        }
    }
}

extern "C" void kernel_launch(void* const* d_in, const int* in_sizes, int n_in,
                              void* d_out, int out_size, void* d_ws, size_t ws_size,
                              hipStream_t stream)
{
    const float* x      = (const float*)d_in[0];
    const float* W_attn = (const float*)d_in[1];
    const float* W_proj = (const float*)d_in[2];
    float* out = (float*)d_out;

    const size_t xN  = (size_t)MROWS * CDIM;
    const size_t waN = (size_t)CDIM * 3 * CDIM;
    const size_t wpN = (size_t)CDIM * CDIM;
    const size_t qkN = (size_t)BATCH * NH * LDIM * HD;
    const size_t vtN = (size_t)BATCH * NH * HD * LPAD;

    char* p = (char*)d_ws;
    short* Xh  = (short*)p; p += xN * 2;    // aliased later as Yh
    short* Xl  = (short*)p; p += xN * 2;    // aliased later as Yl
    short* Wth = (short*)p; p += waN * 2;
    short* Wtl = (short*)p; p += waN * 2;
    short* Pth = (short*)p; p += wpN * 2;
    short* Ptl = (short*)p; p += wpN * 2;
    short* Qh  = (short*)p; p += qkN * 2;
    short* Ql  = (short*)p; p += qkN * 2;
    short* Kh  = (short*)p; p += qkN * 2;
    short* Kl  = (short*)p; p += qkN * 2;
    short* Vth = (short*)p; p += vtN * 2;
    short* Vtl = (short*)p; p += vtN * 2;
    short* Yh = Xh;   // x dead after QKV GEMM
    short* Yl = Xl;

    convsplit_kernel<<<2048, 256, 0, stream>>>(x, Xh, Xl, (int)(xN / 4));
    transconv_kernel<<<dim3(3 * CDIM / 32, CDIM / 32), 256, 0, stream>>>(
        W_attn, Wth, Wtl, CDIM, 3 * CDIM);
    transconv_kernel<<<dim3(CDIM / 32, CDIM / 32), 256, 0, stream>>>(
        W_proj, Pth, Ptl, CDIM, CDIM);

    gemm_mfma_kernel<0><<<dim3(3 * CDIM / 128, (MROWS + 127) / 128), 256, 0, stream>>>(
        Xh, Xl, Wth, Wtl, Qh, Ql, Kh, Kl, Vth, Vtl, nullptr);

    attn_mfma_kernel<<<dim3((LDIM + 127) / 128, BATCH * NH), 256, 0, stream>>>(
        Qh, Ql, Kh, Kl, Vth, Vtl, Yh, Yl);

    gemm_mfma_kernel<1><<<dim3(CDIM / 128, (MROWS + 127) / 128), 256, 0, stream>>>(
        Yh, Yl, Pth, Ptl, nullptr, nullptr, nullptr, nullptr, nullptr, nullptr, out);
}